// Round 9
// baseline (82.454 us; speedup 1.0000x reference)
//
#include <hip/hip_runtime.h>
#include <stdint.h>

// DSN few-shot classifier, MI355X.
// out[q][w] = log_softmax_w( ||P9_w q||^2 ),  query-norm cancels in softmax.
// P9 = P_colspace - u_min u_min^T;  s_w = ||B^T q||^2 - (u_min . q)^2 with
// B = M K, K = G^{-1/2}  (K G K = I -> exact ONB of colspace(M)).
//
// R8: the 10x10 solve is PARALLEL MATRIX ITERATIONS in LDS (one entry per
// thread, 500 threads): Newton-Schulz for G^{-1/2} (6 iters) + repeated
// squaring of T = I - G/c for v_min (8 squarings). No per-lane arrays, no
// readlane/shfl chains -> immune to the scratch-demotion + serial-stall
// disease that pinned R1-R7's solve at 50-80us (VGPR=20 proved demotion).
//
// ws layout:
//   [0,    2200)  W    : 5*11*10 float (rows 0..9: K rows; row 10: v/sqrt(vGv))
//   [2304, 2504)  idx  : 5*10 int
//   [4096, 167936) Upad: 80*1024 bf16 (way w -> rows 16w..16w+10; rest zero)

typedef __attribute__((ext_vector_type(4))) float f32x4;
typedef __attribute__((ext_vector_type(8))) short s16x8;

#define WS_W_OFF    0
#define WS_IDX_OFF  2304
#define WS_U_OFF    4096

__device__ __forceinline__ unsigned short f2bf(float f) {
  unsigned int u = __float_as_uint(f);
  u += 0x7FFFu + ((u >> 16) & 1u);   // round-to-nearest-even
  return (unsigned short)(u >> 16);
}

// int64 vs int32 one-hot labels detection (validated R0).
__device__ __forceinline__ bool labels_int64(const int* L) {
  int cnt = 0; bool oddz = true;
  #pragma unroll
  for (int t = 0; t < 20; ++t) {
    int v = L[t];
    if (t & 1) { if (v) oddz = false; }
    else       { if (v) cnt++; }
  }
  return oddz && (cnt == 2);
}

__device__ __forceinline__ int cls_of(const int* L, bool is64, int i) {
  int best = -0x7fffffff, c = 0;
  #pragma unroll
  for (int j = 0; j < 5; ++j) {
    int v = is64 ? L[i * 10 + 2 * j] : L[i * 5 + j];
    if (v > best) { best = v; c = j; }
  }
  return c;
}

// ---- Kernel A: prep (gram + parallel solve), 1 block x 512 threads --------
__global__ __launch_bounds__(512, 1) void dsn_prep(const float* __restrict__ support,
                                                   const int* __restrict__ labels,
                                                   float* __restrict__ W,
                                                   int* __restrict__ idx) {
  __shared__ float Gf[5][100];     // Gram fp32 (fp64-accumulated)
  __shared__ float Ysm[5][100], Zsm[5][100], Psm[5][100];
  __shared__ float red[5][16];
  __shared__ float cway[5];
  __shared__ int   cls[50];
  __shared__ int   ids[5][10];
  __shared__ int   jm[5];

  int t = threadIdx.x;
  bool is64 = labels_int64(labels);

  // ---- phase 0: class membership ----
  if (t < 50) cls[t] = cls_of(labels, is64, t);
  __syncthreads();
  if (t < 5) {
    int s = 0;
    for (int i = 0; i < 50; ++i)
      if (cls[i] == t) { ids[t][s] = i; idx[t * 10 + s] = i; s++; }
  }
  __syncthreads();

  // ---- phase 1: Gram, 8 waves x ~35 pairs, fp64 acc + shfl reduce ----
  {
    int wv = t >> 6, lane = t & 63;
    #pragma unroll 1
    for (int p = wv; p < 275; p += 8) {
      int w = p / 55, pr = p % 55;
      int a = 0, pp = pr;
      while (pp >= 10 - a) { pp -= 10 - a; a++; }
      int b = a + pp;                // a <= b
      const float* A = support + (size_t)ids[w][a] * 1024;
      const float* B = support + (size_t)ids[w][b] * 1024;
      double acc = 0.0;
      #pragma unroll
      for (int i = 0; i < 16; ++i) {
        int d = lane + 64 * i;
        acc += (double)A[d] * (double)B[d];
      }
      #pragma unroll
      for (int off = 32; off > 0; off >>= 1) acc += __shfl_xor(acc, off);
      if (lane == 0) {
        Gf[w][a * 10 + b] = (float)acc;
        Gf[w][b * 10 + a] = (float)acc;
      }
    }
  }
  __syncthreads();

  // ---- phase 2: parallel solve; thread = (way w, entry e=(i,j)) ----
  bool act = (t < 500);
  int w = t / 100, e = t % 100, i = e / 10, j = e % 10;
  if (!act) { w = 0; e = 0; i = 0; j = 0; }

  // c = Gershgorin upper bound on lambda_max: max_i sum_k |G[i][k]|
  if (act && j == 0 && i < 10) {      // threads e = 0,10,..,90: row i
    float r = 0.f;
    #pragma unroll
    for (int k = 0; k < 10; ++k) r += fabsf(Gf[w][i * 10 + k]);
    red[w][i] = r;
  }
  __syncthreads();
  if (act && e == 0) {
    float m = red[w][0];
    #pragma unroll
    for (int k = 1; k < 10; ++k) m = fmaxf(m, red[w][k]);
    cway[w] = m;
  }
  __syncthreads();

  // init: Y = S = G/c, Z = I
  float cinv = 1.f / cway[w];
  if (act) {
    Ysm[w][e] = Gf[w][e] * cinv;
    Zsm[w][e] = (i == j) ? 1.f : 0.f;
  }
  __syncthreads();

  // Newton-Schulz: Y->S^{1/2}, Z->S^{-1/2} (6 iters, quadratic; spec(S)⊂(0,1])
  #pragma unroll 1
  for (int it = 0; it < 6; ++it) {
    if (act) {
      float p = 0.f;
      #pragma unroll
      for (int k = 0; k < 10; ++k) p += Zsm[w][i * 10 + k] * Ysm[w][k * 10 + j];
      Psm[w][e] = p;
    }
    __syncthreads();
    float yn = 0.f, zn = 0.f;
    if (act) {
      float ay = 0.f, az = 0.f;
      #pragma unroll
      for (int k = 0; k < 10; ++k) {
        ay += Ysm[w][i * 10 + k] * Psm[w][k * 10 + j];
        az += Psm[w][i * 10 + k] * Zsm[w][k * 10 + j];
      }
      yn = 1.5f * Ysm[w][e] - 0.5f * ay;
      zn = 1.5f * Zsm[w][e] - 0.5f * az;
    }
    __syncthreads();
    if (act) { Ysm[w][e] = yn; Zsm[w][e] = zn; }
    __syncthreads();
  }

  // K = G^{-1/2} = Z / sqrt(c); W rows 0..9 (K symmetric)
  if (act) W[(w * 11 + i) * 10 + j] = Zsm[w][e] * rsqrtf(cway[w]);

  // ---- v_min via squaring T = I - S (reuse Ysm for T, Psm for T^2) ----
  if (act) Ysm[w][e] = ((i == j) ? 1.f : 0.f) - Gf[w][e] * cinv;
  __syncthreads();
  #pragma unroll 1
  for (int sq = 0; sq < 8; ++sq) {
    if (act) {
      float p = 0.f;
      #pragma unroll
      for (int k = 0; k < 10; ++k) p += Ysm[w][i * 10 + k] * Ysm[w][k * 10 + j];
      Psm[w][e] = p;
    }
    __syncthreads();
    if (act && j == 0 && i < 10) {
      float m = 0.f;
      #pragma unroll
      for (int k = 0; k < 10; ++k) m = fmaxf(m, fabsf(Psm[w][i * 10 + k]));
      red[w][i] = m;
    }
    __syncthreads();
    if (act && e == 0) {
      float m = red[w][0];
      #pragma unroll
      for (int k = 1; k < 10; ++k) m = fmaxf(m, red[w][k]);
      red[w][15] = 1.f / m;
    }
    __syncthreads();
    if (act) Ysm[w][e] = Psm[w][e] * red[w][15];
    __syncthreads();
  }

  // v = column jmax (max diagonal of T^256 ~ v v^T)
  if (act && e == 0) {
    int best = 0; float bv = Ysm[w][0];
    #pragma unroll
    for (int k = 1; k < 10; ++k) {
      float dk = Ysm[w][k * 10 + k];
      if (dk > bv) { bv = dk; best = k; }
    }
    jm[w] = best;
  }
  __syncthreads();
  if (act && e < 10) red[w][e] = Ysm[w][e * 10 + jm[w]];   // v_e
  __syncthreads();
  if (act && e == 0) {                                      // denom = v^T G v
    float denom = 0.f;
    #pragma unroll
    for (int a2 = 0; a2 < 10; ++a2) {
      float gv = 0.f;
      #pragma unroll
      for (int k = 0; k < 10; ++k) gv += Gf[w][a2 * 10 + k] * red[w][k];
      denom += red[w][a2] * gv;
    }
    red[w][14] = denom;
  }
  __syncthreads();
  // W row 10 = v / sqrt(v^T G v)  (scale-invariant in v)
  if (act && e < 10)
    W[(w * 11 + 10) * 10 + e] = red[w][e] * rsqrtf(red[w][14]);
}

// ---------------- Kernel A2: materialize Upad (80 x 1024 bf16) -------------
__global__ void dsn_basis(const float* __restrict__ support,
                          const float* __restrict__ W,
                          const int* __restrict__ idx,
                          unsigned short* __restrict__ U) {
  int r = blockIdx.x;              // 0..79
  int w = r >> 4, kk = r & 15;
  unsigned short* Urow = U + r * 1024;
  if (kk >= 11) {
    for (int d = threadIdx.x; d < 1024; d += 256) Urow[d] = 0;
    return;
  }
  float wv[10]; int id[10];
  #pragma unroll
  for (int s = 0; s < 10; ++s) {
    wv[s] = W[(w * 11 + kk) * 10 + s];
    id[s] = idx[w * 10 + s];
  }
  for (int d = threadIdx.x; d < 1024; d += 256) {
    float sum = 0.f;
    #pragma unroll
    for (int s = 0; s < 10; ++s) sum += support[id[s] * 1024 + d] * wv[s];
    Urow[d] = f2bf(sum);
  }
}

// ---------------- Kernel B: main — MFMA coeffs + log_softmax ---------------
// 16 queries per wave. A = Upad (5 row-tiles, one per way), B = Q^T fragment.
// D[row=channel][col=query]: col = lane&15, row = (lane>>4)*4 + reg  (m89).
// Row 10 (u_min) lives at lane-group 2, reg 2 -> its square is SUBTRACTED.
__global__ __launch_bounds__(256) void dsn_main(const float* __restrict__ query,
                                                const unsigned short* __restrict__ U,
                                                float* __restrict__ out) {
  int wid  = blockIdx.x * 4 + (threadIdx.x >> 6);
  int lane = threadIdx.x & 63;
  int q0   = wid * 16;
  int qrow = lane & 15;
  int kbase = (lane >> 4) * 8;

  const float* qp = query + (size_t)(q0 + qrow) * 1024 + kbase;
  const unsigned short* up = U + qrow * 1024 + kbase;

  f32x4 acc[5];
  #pragma unroll
  for (int w = 0; w < 5; ++w) acc[w] = (f32x4){0.f, 0.f, 0.f, 0.f};

  #pragma unroll 4
  for (int kt = 0; kt < 32; ++kt) {
    const float* qk = qp + kt * 32;
    f32x4 lo = *(const f32x4*)qk;
    f32x4 hi = *(const f32x4*)(qk + 4);
    s16x8 bf;
    bf[0] = (short)f2bf(lo[0]); bf[1] = (short)f2bf(lo[1]);
    bf[2] = (short)f2bf(lo[2]); bf[3] = (short)f2bf(lo[3]);
    bf[4] = (short)f2bf(hi[0]); bf[5] = (short)f2bf(hi[1]);
    bf[6] = (short)f2bf(hi[2]); bf[7] = (short)f2bf(hi[3]);
    const unsigned short* uk = up + kt * 32;
    #pragma unroll
    for (int w = 0; w < 5; ++w) {
      s16x8 av = *(const s16x8*)(uk + w * 16384);   // row w*16 + qrow
      acc[w] = __builtin_amdgcn_mfma_f32_16x16x32_bf16(av, bf, acc[w], 0, 0, 0);
    }
  }

  // s_w = sum_{rows 0..9} c^2 - c_10^2 (rows 11..15 zero-padded)
  float sgn2 = ((lane >> 4) == 2) ? -1.f : 1.f;   // reg 2 of group 2 = row 10
  float sv[5];
  #pragma unroll
  for (int w = 0; w < 5; ++w) {
    float tcc = acc[w][0] * acc[w][0] + acc[w][1] * acc[w][1] +
                sgn2 * acc[w][2] * acc[w][2] + acc[w][3] * acc[w][3];
    tcc += __shfl_xor(tcc, 16);
    tcc += __shfl_xor(tcc, 32);
    sv[w] = tcc;
  }
  float mx = fmaxf(fmaxf(fmaxf(sv[0], sv[1]), fmaxf(sv[2], sv[3])), sv[4]);
  float sum = 0.f;
  #pragma unroll
  for (int w = 0; w < 5; ++w) sum += expf(sv[w] - mx);
  float lse = mx + logf(sum);
  if (lane < 16) {
    float* o = out + (size_t)(q0 + lane) * 5;
    #pragma unroll
    for (int w = 0; w < 5; ++w) o[w] = sv[w] - lse;
  }
}

extern "C" void kernel_launch(void* const* d_in, const int* in_sizes, int n_in,
                              void* d_out, int out_size, void* d_ws, size_t ws_size,
                              hipStream_t stream) {
  const float* support = (const float*)d_in[0];
  const int*   labels  = (const int*)d_in[1];
  const float* query   = (const float*)d_in[2];
  float* out = (float*)d_out;
  char* ws = (char*)d_ws;

  float*          W   = (float*)(ws + WS_W_OFF);
  int*            idx = (int*)(ws + WS_IDX_OFF);
  unsigned short* U   = (unsigned short*)(ws + WS_U_OFF);

  int nq = in_sizes[2] / 1024;          // 16384
  int nwaves = nq / 16;                 // 1024
  int nblocks = (nwaves + 3) / 4;       // 256

  hipLaunchKernelGGL(dsn_prep,  dim3(1),  dim3(512), 0, stream, support, labels, W, idx);
  hipLaunchKernelGGL(dsn_basis, dim3(80), dim3(256), 0, stream, support, W, idx, U);
  hipLaunchKernelGGL(dsn_main,  dim3(nblocks), dim3(256), 0, stream, query, U, out);
}

// Round 10
// 53.994 us; speedup vs baseline: 1.5271x; 1.5271x over previous
//
#include <hip/hip_runtime.h>
#include <stdint.h>

// DSN few-shot classifier, MI355X.
// out[q][w] = log_softmax_w( ||P9_w q||^2 ),  query-norm cancels in softmax.
// P9 = P_colspace - u_min u_min^T;  s_w = ||B^T q||^2 - (u_min . q)^2 with
// B = M K, K = G^{-1/2}  (K G K = I -> exact ONB of colspace(M)).
//
// R9 structure (each phase in its widest-parallel proven-fast form):
//   dsn_gram : 69 blocks, one wave per (w,a,b) pair  (R1, ~2-3us) + idx
//   dsn_solve: 1 block x 512, R8's parallel LDS solve ONLY (4KB input)
//   dsn_basis: 80 blocks (R1, ~2us)
//   dsn_main : 256 blocks MFMA + log_softmax (R1, ~4us; query L3-resident)
//
// ws layout:
//   [0,    4000)  G    : 5*10*10 double
//   [4096, 6296)  W    : 5*11*10 float (rows 0..9: K rows; row 10: v/sqrt(vGv))
//   [6400, 6600)  idx  : 5*10 int
//   [8192, 172032) Upad: 80*1024 bf16 (way w -> rows 16w..16w+10; rest zero)

typedef __attribute__((ext_vector_type(4))) float f32x4;
typedef __attribute__((ext_vector_type(8))) short s16x8;

#define WS_G_OFF    0
#define WS_W_OFF    4096
#define WS_IDX_OFF  6400
#define WS_U_OFF    8192

__device__ __forceinline__ unsigned short f2bf(float f) {
  unsigned int u = __float_as_uint(f);
  u += 0x7FFFu + ((u >> 16) & 1u);   // round-to-nearest-even
  return (unsigned short)(u >> 16);
}

// int64 vs int32 one-hot labels detection (validated R0).
__device__ __forceinline__ bool labels_int64(const int* L) {
  int cnt = 0; bool oddz = true;
  #pragma unroll
  for (int t = 0; t < 20; ++t) {
    int v = L[t];
    if (t & 1) { if (v) oddz = false; }
    else       { if (v) cnt++; }
  }
  return oddz && (cnt == 2);
}

__device__ __forceinline__ int cls_of(const int* L, bool is64, int i) {
  int best = -0x7fffffff, c = 0;
  #pragma unroll
  for (int j = 0; j < 5; ++j) {
    int v = is64 ? L[i * 10 + 2 * j] : L[i * 5 + j];
    if (v > best) { best = v; c = j; }
  }
  return c;
}

// ---------------- Kernel A1: Gram matrices, one wave per (w,a,b) pair -------
__global__ void dsn_gram(const float* __restrict__ support,
                         const int* __restrict__ labels,
                         double* __restrict__ G,
                         int* __restrict__ idx) {
  int wid  = blockIdx.x * 4 + (threadIdx.x >> 6);
  int lane = threadIdx.x & 63;
  if (wid >= 275) return;               // 5 ways * 55 upper-tri pairs
  int w = wid / 55, p = wid % 55;
  int a = 0;
  while (p >= 10 - a) { p -= 10 - a; a++; }
  int b = a + p;                        // a <= b

  bool is64 = labels_int64(labels);
  int myc = (lane < 50) ? cls_of(labels, is64, lane) : -1;
  unsigned long long mask = __ballot(lane < 50 && myc == w);

  // pair (0,0) waves also publish this way's support indices
  if (wid % 55 == 0 && lane < 10) {
    unsigned long long m2 = mask;
    for (int z = 0; z < lane; ++z) m2 &= m2 - 1;
    idx[w * 10 + lane] = __ffsll(m2) - 1;
  }

  unsigned long long m = mask;
  for (int i = 0; i < a; ++i) m &= m - 1;
  int ia = __ffsll((unsigned long long)m) - 1;
  m = mask;
  for (int i = 0; i < b; ++i) m &= m - 1;
  int ib = __ffsll((unsigned long long)m) - 1;

  const float* A = support + ia * 1024;
  const float* B = support + ib * 1024;
  double acc = 0.0;
  #pragma unroll
  for (int i = 0; i < 16; ++i) {
    int d = lane + 64 * i;
    acc += (double)A[d] * (double)B[d];
  }
  #pragma unroll
  for (int off = 32; off > 0; off >>= 1) acc += __shfl_xor(acc, off);
  if (lane == 0) {
    G[(w * 10 + a) * 10 + b] = acc;
    G[(w * 10 + b) * 10 + a] = acc;
  }
}

// ---- Kernel A2: parallel solve in LDS (R8 phase 2; validated numerics) ----
// thread = (way w, entry e=(i,j)); 500 active of 512; ~48 barrier phases.
__global__ __launch_bounds__(512, 1) void dsn_solve(const double* __restrict__ G,
                                                    float* __restrict__ W) {
  __shared__ float Gf[5][100];
  __shared__ float Ysm[5][100], Zsm[5][100], Psm[5][100];
  __shared__ float red[5][16];
  __shared__ float cway[5];
  __shared__ int   jm[5];

  int t = threadIdx.x;
  bool act = (t < 500);
  int w = t / 100, e = t % 100, i = e / 10, j = e % 10;
  if (!act) { w = 0; e = 0; i = 0; j = 0; }

  if (act) Gf[w][e] = (float)G[w * 100 + e];
  __syncthreads();

  // c = Gershgorin upper bound on lambda_max
  if (act && j == 0) {
    float r = 0.f;
    #pragma unroll
    for (int k = 0; k < 10; ++k) r += fabsf(Gf[w][i * 10 + k]);
    red[w][i] = r;
  }
  __syncthreads();
  if (act && e == 0) {
    float m = red[w][0];
    #pragma unroll
    for (int k = 1; k < 10; ++k) m = fmaxf(m, red[w][k]);
    cway[w] = m;
  }
  __syncthreads();

  // init: Y = S = G/c, Z = I
  float cinv = 1.f / cway[w];
  if (act) {
    Ysm[w][e] = Gf[w][e] * cinv;
    Zsm[w][e] = (i == j) ? 1.f : 0.f;
  }
  __syncthreads();

  // Newton-Schulz: Y->S^{1/2}, Z->S^{-1/2} (6 iters; spec(S) in (0,1])
  #pragma unroll 1
  for (int it = 0; it < 6; ++it) {
    if (act) {
      float p = 0.f;
      #pragma unroll
      for (int k = 0; k < 10; ++k) p += Zsm[w][i * 10 + k] * Ysm[w][k * 10 + j];
      Psm[w][e] = p;
    }
    __syncthreads();
    float yn = 0.f, zn = 0.f;
    if (act) {
      float ay = 0.f, az = 0.f;
      #pragma unroll
      for (int k = 0; k < 10; ++k) {
        ay += Ysm[w][i * 10 + k] * Psm[w][k * 10 + j];
        az += Psm[w][i * 10 + k] * Zsm[w][k * 10 + j];
      }
      yn = 1.5f * Ysm[w][e] - 0.5f * ay;
      zn = 1.5f * Zsm[w][e] - 0.5f * az;
    }
    __syncthreads();
    if (act) { Ysm[w][e] = yn; Zsm[w][e] = zn; }
    __syncthreads();
  }

  // K = G^{-1/2} = Z / sqrt(c); W rows 0..9
  if (act) W[(w * 11 + i) * 10 + j] = Zsm[w][e] * rsqrtf(cway[w]);

  // v_min via repeated squaring of T = I - S (8 squarings, max-normalized)
  if (act) Ysm[w][e] = ((i == j) ? 1.f : 0.f) - Gf[w][e] * cinv;
  __syncthreads();
  #pragma unroll 1
  for (int sq = 0; sq < 8; ++sq) {
    if (act) {
      float p = 0.f;
      #pragma unroll
      for (int k = 0; k < 10; ++k) p += Ysm[w][i * 10 + k] * Ysm[w][k * 10 + j];
      Psm[w][e] = p;
    }
    __syncthreads();
    if (act && j == 0) {
      float m = 0.f;
      #pragma unroll
      for (int k = 0; k < 10; ++k) m = fmaxf(m, fabsf(Psm[w][i * 10 + k]));
      red[w][i] = m;
    }
    __syncthreads();
    if (act) {
      float m = red[w][0];                 // redundant per-thread combine
      #pragma unroll
      for (int k = 1; k < 10; ++k) m = fmaxf(m, red[w][k]);
      Ysm[w][e] = Psm[w][e] * (1.f / m);
    }
    __syncthreads();
  }

  // v = column of max diagonal (T^256 ~ v v^T)
  if (act && e == 0) {
    int best = 0; float bv = Ysm[w][0];
    #pragma unroll
    for (int k = 1; k < 10; ++k) {
      float dk = Ysm[w][k * 10 + k];
      if (dk > bv) { bv = dk; best = k; }
    }
    jm[w] = best;
  }
  __syncthreads();
  if (act && e < 10) red[w][e] = Ysm[w][e * 10 + jm[w]];   // v_e
  __syncthreads();
  if (act && e == 0) {                                      // denom = v^T G v
    float denom = 0.f;
    #pragma unroll
    for (int a2 = 0; a2 < 10; ++a2) {
      float gv = 0.f;
      #pragma unroll
      for (int k = 0; k < 10; ++k) gv += Gf[w][a2 * 10 + k] * red[w][k];
      denom += red[w][a2] * gv;
    }
    red[w][14] = denom;
  }
  __syncthreads();
  if (act && e < 10)
    W[(w * 11 + 10) * 10 + e] = red[w][e] * rsqrtf(red[w][14]);
}

// ---------------- Kernel A3: materialize Upad (80 x 1024 bf16) -------------
__global__ void dsn_basis(const float* __restrict__ support,
                          const float* __restrict__ W,
                          const int* __restrict__ idx,
                          unsigned short* __restrict__ U) {
  int r = blockIdx.x;              // 0..79
  int w = r >> 4, kk = r & 15;
  unsigned short* Urow = U + r * 1024;
  if (kk >= 11) {
    for (int d = threadIdx.x; d < 1024; d += 256) Urow[d] = 0;
    return;
  }
  float wv[10]; int id[10];
  #pragma unroll
  for (int s = 0; s < 10; ++s) {
    wv[s] = W[(w * 11 + kk) * 10 + s];
    id[s] = idx[w * 10 + s];
  }
  for (int d = threadIdx.x; d < 1024; d += 256) {
    float sum = 0.f;
    #pragma unroll
    for (int s = 0; s < 10; ++s) sum += support[id[s] * 1024 + d] * wv[s];
    Urow[d] = f2bf(sum);
  }
}

// ---------------- Kernel B: main — MFMA coeffs + log_softmax ---------------
// 16 queries per wave. A = Upad (5 row-tiles, one per way), B = Q^T fragment.
// D[row=channel][col=query]: col = lane&15, row = (lane>>4)*4 + reg  (m89).
// Row 10 (u_min) lives at lane-group 2, reg 2 -> its square is SUBTRACTED.
__global__ __launch_bounds__(256) void dsn_main(const float* __restrict__ query,
                                                const unsigned short* __restrict__ U,
                                                float* __restrict__ out) {
  int wid  = blockIdx.x * 4 + (threadIdx.x >> 6);
  int lane = threadIdx.x & 63;
  int q0   = wid * 16;
  int qrow = lane & 15;
  int kbase = (lane >> 4) * 8;

  const float* qp = query + (size_t)(q0 + qrow) * 1024 + kbase;
  const unsigned short* up = U + qrow * 1024 + kbase;

  f32x4 acc[5];
  #pragma unroll
  for (int w = 0; w < 5; ++w) acc[w] = (f32x4){0.f, 0.f, 0.f, 0.f};

  #pragma unroll 4
  for (int kt = 0; kt < 32; ++kt) {
    const float* qk = qp + kt * 32;
    f32x4 lo = *(const f32x4*)qk;
    f32x4 hi = *(const f32x4*)(qk + 4);
    s16x8 bf;
    bf[0] = (short)f2bf(lo[0]); bf[1] = (short)f2bf(lo[1]);
    bf[2] = (short)f2bf(lo[2]); bf[3] = (short)f2bf(lo[3]);
    bf[4] = (short)f2bf(hi[0]); bf[5] = (short)f2bf(hi[1]);
    bf[6] = (short)f2bf(hi[2]); bf[7] = (short)f2bf(hi[3]);
    const unsigned short* uk = up + kt * 32;
    #pragma unroll
    for (int w = 0; w < 5; ++w) {
      s16x8 av = *(const s16x8*)(uk + w * 16384);   // row w*16 + qrow
      acc[w] = __builtin_amdgcn_mfma_f32_16x16x32_bf16(av, bf, acc[w], 0, 0, 0);
    }
  }

  // s_w = sum_{rows 0..9} c^2 - c_10^2 (rows 11..15 zero-padded)
  float sgn2 = ((lane >> 4) == 2) ? -1.f : 1.f;   // reg 2 of group 2 = row 10
  float sv[5];
  #pragma unroll
  for (int w = 0; w < 5; ++w) {
    float tcc = acc[w][0] * acc[w][0] + acc[w][1] * acc[w][1] +
                sgn2 * acc[w][2] * acc[w][2] + acc[w][3] * acc[w][3];
    tcc += __shfl_xor(tcc, 16);
    tcc += __shfl_xor(tcc, 32);
    sv[w] = tcc;
  }
  float mx = fmaxf(fmaxf(fmaxf(sv[0], sv[1]), fmaxf(sv[2], sv[3])), sv[4]);
  float sum = 0.f;
  #pragma unroll
  for (int w = 0; w < 5; ++w) sum += expf(sv[w] - mx);
  float lse = mx + logf(sum);
  if (lane < 16) {
    float* o = out + (size_t)(q0 + lane) * 5;
    #pragma unroll
    for (int w = 0; w < 5; ++w) o[w] = sv[w] - lse;
  }
}

extern "C" void kernel_launch(void* const* d_in, const int* in_sizes, int n_in,
                              void* d_out, int out_size, void* d_ws, size_t ws_size,
                              hipStream_t stream) {
  const float* support = (const float*)d_in[0];
  const int*   labels  = (const int*)d_in[1];
  const float* query   = (const float*)d_in[2];
  float* out = (float*)d_out;
  char* ws = (char*)d_ws;

  double*         G   = (double*)(ws + WS_G_OFF);
  float*          W   = (float*)(ws + WS_W_OFF);
  int*            idx = (int*)(ws + WS_IDX_OFF);
  unsigned short* U   = (unsigned short*)(ws + WS_U_OFF);

  int nq = in_sizes[2] / 1024;          // 16384
  int nwaves = nq / 16;                 // 1024
  int nblocks = (nwaves + 3) / 4;       // 256

  hipLaunchKernelGGL(dsn_gram,  dim3(69), dim3(256), 0, stream, support, labels, G, idx);
  hipLaunchKernelGGL(dsn_solve, dim3(1),  dim3(512), 0, stream, G, W);
  hipLaunchKernelGGL(dsn_basis, dim3(80), dim3(256), 0, stream, support, W, idx, U);
  hipLaunchKernelGGL(dsn_main,  dim3(nblocks), dim3(256), 0, stream, query, U, out);
}

// Round 11
// 49.423 us; speedup vs baseline: 1.6683x; 1.0925x over previous
//
#include <hip/hip_runtime.h>
#include <stdint.h>

// DSN few-shot classifier, MI355X.
// out[q][w] = log_softmax_w( ||P9_w q||^2 ),  query-norm cancels in softmax.
// P9 = P_colspace - u_min u_min^T;  s_w = ||B^T q||^2 - (u_min . q)^2 with
// B = M K, K = G^{-1/2}  (K G K = I -> exact ONB of colspace(M)).
//
// R10: dsn_solve = 5 blocks x 64 threads (ONE WAVE per way). Single-wave
// blocks make every __syncthreads intra-wave (~100cyc) instead of an 8-wave
// barrier (~1-2Kcyc x 48 phases = the ~35us R9 residual). Lane t<50 owns
// matrix entries 2t, 2t+1; all branches uniform; fixed iteration counts.
//
// ws layout:
//   [0,    4000)  G    : 5*10*10 double
//   [4096, 6296)  W    : 5*11*10 float (rows 0..9: K rows; row 10: v/sqrt(vGv))
//   [6400, 6600)  idx  : 5*10 int
//   [8192, 172032) Upad: 80*1024 bf16 (way w -> rows 16w..16w+10; rest zero)

typedef __attribute__((ext_vector_type(4))) float f32x4;
typedef __attribute__((ext_vector_type(8))) short s16x8;

#define WS_G_OFF    0
#define WS_W_OFF    4096
#define WS_IDX_OFF  6400
#define WS_U_OFF    8192

__device__ __forceinline__ unsigned short f2bf(float f) {
  unsigned int u = __float_as_uint(f);
  u += 0x7FFFu + ((u >> 16) & 1u);   // round-to-nearest-even
  return (unsigned short)(u >> 16);
}

// int64 vs int32 one-hot labels detection (validated R0).
__device__ __forceinline__ bool labels_int64(const int* L) {
  int cnt = 0; bool oddz = true;
  #pragma unroll
  for (int t = 0; t < 20; ++t) {
    int v = L[t];
    if (t & 1) { if (v) oddz = false; }
    else       { if (v) cnt++; }
  }
  return oddz && (cnt == 2);
}

__device__ __forceinline__ int cls_of(const int* L, bool is64, int i) {
  int best = -0x7fffffff, c = 0;
  #pragma unroll
  for (int j = 0; j < 5; ++j) {
    int v = is64 ? L[i * 10 + 2 * j] : L[i * 5 + j];
    if (v > best) { best = v; c = j; }
  }
  return c;
}

// ---------------- Kernel A1: Gram matrices, one wave per (w,a,b) pair -------
__global__ void dsn_gram(const float* __restrict__ support,
                         const int* __restrict__ labels,
                         double* __restrict__ G,
                         int* __restrict__ idx) {
  int wid  = blockIdx.x * 4 + (threadIdx.x >> 6);
  int lane = threadIdx.x & 63;
  if (wid >= 275) return;               // 5 ways * 55 upper-tri pairs
  int w = wid / 55, p = wid % 55;
  int a = 0;
  while (p >= 10 - a) { p -= 10 - a; a++; }
  int b = a + p;                        // a <= b

  bool is64 = labels_int64(labels);
  int myc = (lane < 50) ? cls_of(labels, is64, lane) : -1;
  unsigned long long mask = __ballot(lane < 50 && myc == w);

  // pair (0,0) waves also publish this way's support indices
  if (wid % 55 == 0 && lane < 10) {
    unsigned long long m2 = mask;
    for (int z = 0; z < lane; ++z) m2 &= m2 - 1;
    idx[w * 10 + lane] = __ffsll(m2) - 1;
  }

  unsigned long long m = mask;
  for (int i = 0; i < a; ++i) m &= m - 1;
  int ia = __ffsll((unsigned long long)m) - 1;
  m = mask;
  for (int i = 0; i < b; ++i) m &= m - 1;
  int ib = __ffsll((unsigned long long)m) - 1;

  const float* A = support + ia * 1024;
  const float* B = support + ib * 1024;
  double acc = 0.0;
  #pragma unroll
  for (int i = 0; i < 16; ++i) {
    int d = lane + 64 * i;
    acc += (double)A[d] * (double)B[d];
  }
  #pragma unroll
  for (int off = 32; off > 0; off >>= 1) acc += __shfl_xor(acc, off);
  if (lane == 0) {
    G[(w * 10 + a) * 10 + b] = acc;
    G[(w * 10 + b) * 10 + a] = acc;
  }
}

// ---- Kernel A2: parallel solve, ONE WAVE PER WAY (5 blocks x 64) ----------
// Lane t<50 owns entries e0=2t, e1=2t+1 of the 10x10 matrices in LDS.
// All __syncthreads are single-wave (cheap); all branches uniform.
__global__ __launch_bounds__(64, 1) void dsn_solve(const double* __restrict__ G,
                                                   float* __restrict__ W) {
  __shared__ float Gf[100], Ysm[100], Zsm[100], Psm[100];
  __shared__ float red[16];
  __shared__ int   jm[1];

  int w = blockIdx.x, t = threadIdx.x;
  bool act = (t < 50);
  int e0 = 2 * t, e1 = 2 * t + 1;
  int i0 = e0 / 10, j0 = e0 % 10;
  int i1 = e1 / 10, j1 = e1 % 10;
  if (!act) { e0 = 0; e1 = 1; i0 = 0; j0 = 0; i1 = 0; j1 = 1; }

  if (act) {
    Gf[e0] = (float)G[w * 100 + e0];
    Gf[e1] = (float)G[w * 100 + e1];
  }
  __syncthreads();

  // c = Gershgorin upper bound on lambda_max
  if (t < 10) {
    float r = 0.f;
    #pragma unroll
    for (int k = 0; k < 10; ++k) r += fabsf(Gf[t * 10 + k]);
    red[t] = r;
  }
  __syncthreads();
  float c = red[0];
  #pragma unroll
  for (int k = 1; k < 10; ++k) c = fmaxf(c, red[k]);
  float cinv = 1.f / c;

  // init: Y = S = G/c, Z = I
  if (act) {
    Ysm[e0] = Gf[e0] * cinv;  Ysm[e1] = Gf[e1] * cinv;
    Zsm[e0] = (i0 == j0) ? 1.f : 0.f;
    Zsm[e1] = (i1 == j1) ? 1.f : 0.f;
  }
  __syncthreads();

  // Newton-Schulz: Y->S^{1/2}, Z->S^{-1/2} (6 iters; spec(S) in (0,1])
  #pragma unroll 1
  for (int it = 0; it < 6; ++it) {
    if (act) {
      float p0 = 0.f, p1 = 0.f;
      #pragma unroll
      for (int k = 0; k < 10; ++k) {
        p0 += Zsm[i0 * 10 + k] * Ysm[k * 10 + j0];
        p1 += Zsm[i1 * 10 + k] * Ysm[k * 10 + j1];
      }
      Psm[e0] = p0; Psm[e1] = p1;
    }
    __syncthreads();
    float y0 = 0.f, y1 = 0.f, z0 = 0.f, z1 = 0.f;
    if (act) {
      float ay0 = 0.f, az0 = 0.f, ay1 = 0.f, az1 = 0.f;
      #pragma unroll
      for (int k = 0; k < 10; ++k) {
        ay0 += Ysm[i0 * 10 + k] * Psm[k * 10 + j0];
        az0 += Psm[i0 * 10 + k] * Zsm[k * 10 + j0];
        ay1 += Ysm[i1 * 10 + k] * Psm[k * 10 + j1];
        az1 += Psm[i1 * 10 + k] * Zsm[k * 10 + j1];
      }
      y0 = 1.5f * Ysm[e0] - 0.5f * ay0;
      z0 = 1.5f * Zsm[e0] - 0.5f * az0;
      y1 = 1.5f * Ysm[e1] - 0.5f * ay1;
      z1 = 1.5f * Zsm[e1] - 0.5f * az1;
    }
    __syncthreads();
    if (act) { Ysm[e0] = y0; Ysm[e1] = y1; Zsm[e0] = z0; Zsm[e1] = z1; }
    __syncthreads();
  }

  // K = G^{-1/2} = Z / sqrt(c); W rows 0..9
  float rsc = rsqrtf(c);
  if (act) {
    W[(w * 11 + i0) * 10 + j0] = Zsm[e0] * rsc;
    W[(w * 11 + i1) * 10 + j1] = Zsm[e1] * rsc;
  }

  // v_min via repeated squaring of T = I - S (8 squarings, max-normalized)
  if (act) {
    Ysm[e0] = ((i0 == j0) ? 1.f : 0.f) - Gf[e0] * cinv;
    Ysm[e1] = ((i1 == j1) ? 1.f : 0.f) - Gf[e1] * cinv;
  }
  __syncthreads();
  #pragma unroll 1
  for (int sq = 0; sq < 8; ++sq) {
    if (act) {
      float p0 = 0.f, p1 = 0.f;
      #pragma unroll
      for (int k = 0; k < 10; ++k) {
        p0 += Ysm[i0 * 10 + k] * Ysm[k * 10 + j0];
        p1 += Ysm[i1 * 10 + k] * Ysm[k * 10 + j1];
      }
      Psm[e0] = p0; Psm[e1] = p1;
    }
    __syncthreads();
    if (t < 10) {
      float m = 0.f;
      #pragma unroll
      for (int k = 0; k < 10; ++k) m = fmaxf(m, fabsf(Psm[t * 10 + k]));
      red[t] = m;
    }
    __syncthreads();
    float m = red[0];
    #pragma unroll
    for (int k = 1; k < 10; ++k) m = fmaxf(m, red[k]);
    float minv = 1.f / m;
    if (act) { Ysm[e0] = Psm[e0] * minv; Ysm[e1] = Psm[e1] * minv; }
    __syncthreads();
  }

  // v = column of max diagonal (T^256 ~ v v^T); deterministic serial argmax
  if (t == 0) {
    int best = 0; float bv = Ysm[0];
    #pragma unroll
    for (int k = 1; k < 10; ++k) {
      float dk = Ysm[k * 10 + k];
      if (dk > bv) { bv = dk; best = k; }
    }
    jm[0] = best;
  }
  __syncthreads();
  if (t < 10) red[t] = Ysm[t * 10 + jm[0]];   // v_t
  __syncthreads();
  // denom = v^T G v (redundant per-lane, uniform)
  float denom = 0.f;
  #pragma unroll
  for (int a2 = 0; a2 < 10; ++a2) {
    float gv = 0.f;
    #pragma unroll
    for (int k = 0; k < 10; ++k) gv += Gf[a2 * 10 + k] * red[k];
    denom += red[a2] * gv;
  }
  if (t < 10)
    W[(w * 11 + 10) * 10 + t] = red[t] * rsqrtf(denom);
}

// ---------------- Kernel A3: materialize Upad (80 x 1024 bf16) -------------
__global__ void dsn_basis(const float* __restrict__ support,
                          const float* __restrict__ W,
                          const int* __restrict__ idx,
                          unsigned short* __restrict__ U) {
  int r = blockIdx.x;              // 0..79
  int w = r >> 4, kk = r & 15;
  unsigned short* Urow = U + r * 1024;
  if (kk >= 11) {
    for (int d = threadIdx.x; d < 1024; d += 256) Urow[d] = 0;
    return;
  }
  float wv[10]; int id[10];
  #pragma unroll
  for (int s = 0; s < 10; ++s) {
    wv[s] = W[(w * 11 + kk) * 10 + s];
    id[s] = idx[w * 10 + s];
  }
  for (int d = threadIdx.x; d < 1024; d += 256) {
    float sum = 0.f;
    #pragma unroll
    for (int s = 0; s < 10; ++s) sum += support[id[s] * 1024 + d] * wv[s];
    Urow[d] = f2bf(sum);
  }
}

// ---------------- Kernel B: main — MFMA coeffs + log_softmax ---------------
// 16 queries per wave. A = Upad (5 row-tiles, one per way), B = Q^T fragment.
// D[row=channel][col=query]: col = lane&15, row = (lane>>4)*4 + reg  (m89).
// Row 10 (u_min) lives at lane-group 2, reg 2 -> its square is SUBTRACTED.
__global__ __launch_bounds__(256) void dsn_main(const float* __restrict__ query,
                                                const unsigned short* __restrict__ U,
                                                float* __restrict__ out) {
  int wid  = blockIdx.x * 4 + (threadIdx.x >> 6);
  int lane = threadIdx.x & 63;
  int q0   = wid * 16;
  int qrow = lane & 15;
  int kbase = (lane >> 4) * 8;

  const float* qp = query + (size_t)(q0 + qrow) * 1024 + kbase;
  const unsigned short* up = U + qrow * 1024 + kbase;

  f32x4 acc[5];
  #pragma unroll
  for (int w = 0; w < 5; ++w) acc[w] = (f32x4){0.f, 0.f, 0.f, 0.f};

  #pragma unroll 4
  for (int kt = 0; kt < 32; ++kt) {
    const float* qk = qp + kt * 32;
    f32x4 lo = *(const f32x4*)qk;
    f32x4 hi = *(const f32x4*)(qk + 4);
    s16x8 bf;
    bf[0] = (short)f2bf(lo[0]); bf[1] = (short)f2bf(lo[1]);
    bf[2] = (short)f2bf(lo[2]); bf[3] = (short)f2bf(lo[3]);
    bf[4] = (short)f2bf(hi[0]); bf[5] = (short)f2bf(hi[1]);
    bf[6] = (short)f2bf(hi[2]); bf[7] = (short)f2bf(hi[3]);
    const unsigned short* uk = up + kt * 32;
    #pragma unroll
    for (int w = 0; w < 5; ++w) {
      s16x8 av = *(const s16x8*)(uk + w * 16384);   // row w*16 + qrow
      acc[w] = __builtin_amdgcn_mfma_f32_16x16x32_bf16(av, bf, acc[w], 0, 0, 0);
    }
  }

  // s_w = sum_{rows 0..9} c^2 - c_10^2 (rows 11..15 zero-padded)
  float sgn2 = ((lane >> 4) == 2) ? -1.f : 1.f;   // reg 2 of group 2 = row 10
  float sv[5];
  #pragma unroll
  for (int w = 0; w < 5; ++w) {
    float tcc = acc[w][0] * acc[w][0] + acc[w][1] * acc[w][1] +
                sgn2 * acc[w][2] * acc[w][2] + acc[w][3] * acc[w][3];
    tcc += __shfl_xor(tcc, 16);
    tcc += __shfl_xor(tcc, 32);
    sv[w] = tcc;
  }
  float mx = fmaxf(fmaxf(fmaxf(sv[0], sv[1]), fmaxf(sv[2], sv[3])), sv[4]);
  float sum = 0.f;
  #pragma unroll
  for (int w = 0; w < 5; ++w) sum += expf(sv[w] - mx);
  float lse = mx + logf(sum);
  if (lane < 16) {
    float* o = out + (size_t)(q0 + lane) * 5;
    #pragma unroll
    for (int w = 0; w < 5; ++w) o[w] = sv[w] - lse;
  }
}

extern "C" void kernel_launch(void* const* d_in, const int* in_sizes, int n_in,
                              void* d_out, int out_size, void* d_ws, size_t ws_size,
                              hipStream_t stream) {
  const float* support = (const float*)d_in[0];
  const int*   labels  = (const int*)d_in[1];
  const float* query   = (const float*)d_in[2];
  float* out = (float*)d_out;
  char* ws = (char*)d_ws;

  double*         G   = (double*)(ws + WS_G_OFF);
  float*          W   = (float*)(ws + WS_W_OFF);
  int*            idx = (int*)(ws + WS_IDX_OFF);
  unsigned short* U   = (unsigned short*)(ws + WS_U_OFF);

  int nq = in_sizes[2] / 1024;          // 16384
  int nwaves = nq / 16;                 // 1024
  int nblocks = (nwaves + 3) / 4;       // 256

  hipLaunchKernelGGL(dsn_gram,  dim3(69), dim3(256), 0, stream, support, labels, G, idx);
  hipLaunchKernelGGL(dsn_solve, dim3(5),  dim3(64),  0, stream, G, W);
  hipLaunchKernelGGL(dsn_basis, dim3(80), dim3(256), 0, stream, support, W, idx, U);
  hipLaunchKernelGGL(dsn_main,  dim3(nblocks), dim3(256), 0, stream, query, U, out);
}